// Round 3
// baseline (6453.756 us; speedup 1.0000x reference)
//
#include <hip/hip_runtime.h>
#include <math.h>

// MixedOp (SPDNet DARTS cell): per (b,c): s_k = W_k X W_k^T (k=0..3),
// G0 = sum w_k s_k, Sq=G0^{1/2}, Si=G0^{-1/2} (eigh), T_k = Si s_k Si,
// L_k = logm(T_k) (eigh), U = sum w_k L_k, out = Sq expm(U) Sq (eigh).
// One 256-thread block per (b,c); all matrices f64 in LDS; parallel
// cyclic Jacobi for the 6 eigendecompositions per block.
// Output buffer is FLOAT32 (harness contract: non-bf16 output -> float*).

#define NTH 256
#define LDA 33   // padded f64 row stride for 32x32 LDS matrices

struct SM {
  double sS[4][32 * LDA];  // s_0..s_3; slot 0 becomes U after k=0 consumed
  double sA[32 * LDA];     // Jacobi work (G0 / T / U-copy) ; also Sq*E temp
  double sV[32 * LDA];     // eigenvectors
  double sSq[32 * LDA];    // G0^{1/2}
  double sSi[32 * LDA];    // G0^{-1/2} ; later expm(U)
  double sT1[32 * LDA];    // temp ; aliases W_k f32 tile in phase 1
  double red[NTH];         // reduction scratch
  double cs16[16], sn16[16];
  double ew[32];           // eigenvalues
  double wk[4];            // mixing weights (f64)
  int pr[16], qr[16];
};
// Phase-1 aliases (X f32 [64][65], Y f64 [32][65]) overlay sA..sSi.

__device__ inline void mm_nn(double* __restrict__ D, const double* __restrict__ A,
                             const double* __restrict__ B, int tid) {
  for (int idx = tid; idx < 1024; idx += NTH) {
    int i = idx >> 5, j = idx & 31;
    double acc = 0.0;
#pragma unroll
    for (int m = 0; m < 32; ++m) acc = fma(A[i * LDA + m], B[m * LDA + j], acc);
    D[i * LDA + j] = acc;
  }
}

// D = A * B^T
__device__ inline void mm_nt(double* __restrict__ D, const double* __restrict__ A,
                             const double* __restrict__ B, int tid) {
  for (int idx = tid; idx < 1024; idx += NTH) {
    int i = idx >> 5, j = idx & 31;
    double acc = 0.0;
#pragma unroll
    for (int m = 0; m < 32; ++m) acc = fma(A[i * LDA + m], B[j * LDA + m], acc);
    D[i * LDA + j] = acc;
  }
}

// D = w * (A * B^T)   or   D += w * (A * B^T)
template <bool ACC>
__device__ inline void mm_nt_ws(double* __restrict__ D, const double* __restrict__ A,
                                const double* __restrict__ B, double w, int tid) {
  for (int idx = tid; idx < 1024; idx += NTH) {
    int i = idx >> 5, j = idx & 31;
    double acc = 0.0;
#pragma unroll
    for (int m = 0; m < 32; ++m) acc = fma(A[i * LDA + m], B[j * LDA + m], acc);
    if (ACC) D[i * LDA + j] = fma(w, acc, D[i * LDA + j]);
    else     D[i * LDA + j] = w * acc;
  }
}

// Parallel cyclic Jacobi eigendecomposition of symmetric 32x32 A (in LDS,
// stride LDA). Destroys A; V gets eigenvectors (columns); ew eigenvalues.
__device__ void jacobi_eigh(double* __restrict__ A, double* __restrict__ V,
                            SM& sm, int tid) {
  // V = I
  for (int idx = tid; idx < 1024; idx += NTH) {
    int i = idx >> 5, j = idx & 31;
    V[i * LDA + j] = (i == j) ? 1.0 : 0.0;
  }
  // fro^2 (rotation-invariant) -> tolerance
  double loc = 0.0;
  for (int idx = tid; idx < 1024; idx += NTH) {
    int i = idx >> 5, j = idx & 31;
    double v = A[i * LDA + j];
    loc += v * v;
  }
  sm.red[tid] = loc;
  __syncthreads();
  for (int s = NTH / 2; s > 0; s >>= 1) {
    if (tid < s) sm.red[tid] += sm.red[tid + s];
    __syncthreads();
  }
  double tol2 = 1e-28 * sm.red[0];

  for (int sweep = 0; sweep < 15; ++sweep) {
    // off-diagonal Frobenius^2
    double lo = 0.0;
    for (int idx = tid; idx < 1024; idx += NTH) {
      int i = idx >> 5, j = idx & 31;
      if (i != j) {
        double v = A[i * LDA + j];
        lo += v * v;
      }
    }
    __syncthreads();  // protect red[] from previous read
    sm.red[tid] = lo;
    __syncthreads();
    for (int s = NTH / 2; s > 0; s >>= 1) {
      if (tid < s) sm.red[tid] += sm.red[tid + s];
      __syncthreads();
    }
    if (sm.red[0] <= tol2) break;  // uniform branch

    for (int r = 0; r < 31; ++r) {
      if (tid < 16) {
        int p, q;
        if (tid == 0) { p = 31; q = r % 31; }
        else {
          p = (r + tid) % 31;
          q = (r - tid + 31) % 31;
        }
        if (p > q) { int t = p; p = q; q = t; }
        double app = A[p * LDA + p], aqq = A[q * LDA + q], apq = A[p * LDA + q];
        double c = 1.0, s = 0.0;
        if (fabs(apq) > 1e-300) {
          double tau = (aqq - app) / (2.0 * apq);
          double t = ((tau >= 0.0) ? 1.0 : -1.0) / (fabs(tau) + sqrt(1.0 + tau * tau));
          c = 1.0 / sqrt(1.0 + t * t);
          s = t * c;
        }
        sm.pr[tid] = p; sm.qr[tid] = q; sm.cs16[tid] = c; sm.sn16[tid] = s;
      }
      __syncthreads();
      // row phase: A <- J^T A
      for (int idx = tid; idx < 512; idx += NTH) {
        int pi = idx >> 5, j = idx & 31;
        int p = sm.pr[pi], q = sm.qr[pi];
        double c = sm.cs16[pi], s = sm.sn16[pi];
        double ap = A[p * LDA + j], aq = A[q * LDA + j];
        A[p * LDA + j] = c * ap - s * aq;
        A[q * LDA + j] = s * ap + c * aq;
      }
      __syncthreads();
      // col phase: A <- A J ; V <- V J
      for (int idx = tid; idx < 512; idx += NTH) {
        int pi = idx >> 5, j = idx & 31;
        int p = sm.pr[pi], q = sm.qr[pi];
        double c = sm.cs16[pi], s = sm.sn16[pi];
        double ap = A[j * LDA + p], aq = A[j * LDA + q];
        A[j * LDA + p] = c * ap - s * aq;
        A[j * LDA + q] = s * ap + c * aq;
        ap = V[j * LDA + p]; aq = V[j * LDA + q];
        V[j * LDA + p] = c * ap - s * aq;
        V[j * LDA + q] = s * ap + c * aq;
      }
      __syncthreads();
    }
  }
  if (tid < 32) sm.ew[tid] = A[tid * LDA + tid];
  __syncthreads();
}

__global__ __launch_bounds__(NTH) void mixedop_kernel(
    const float* __restrict__ xg, const float* __restrict__ wg,
    const float* __restrict__ Wg, float* __restrict__ outg) {
  __shared__ SM sm;
  const int bc = blockIdx.x;
  const int tid = threadIdx.x;

  if (tid < 4) sm.wk[tid] = (double)wg[tid];

  // ---- Phase 1: s_k = W_k X W_k^T, X/Y/W staged in aliased LDS ----
  float* Xs = (float*)sm.sA;                           // [64][65] f32, 16640 B
  double* Ys = (double*)((char*)sm.sA + 16640);        // [32][65] f64, 16640 B
  float* Wks = (float*)sm.sT1;                         // [32][65] f32, 8320 B

  const float* xsrc = xg + (size_t)bc * 4096;
  for (int idx = tid; idx < 4096; idx += NTH) {
    int i = idx >> 6, j = idx & 63;
    Xs[i * 65 + j] = xsrc[idx];
  }
  __syncthreads();

  for (int k = 0; k < 4; ++k) {
    const float* wsrc = Wg + k * 2048;
    for (int idx = tid; idx < 2048; idx += NTH) {
      int o = idx >> 6, i = idx & 63;
      Wks[o * 65 + i] = wsrc[idx];
    }
    __syncthreads();
    // Y = W_k * X   [32 x 64]
    for (int idx = tid; idx < 2048; idx += NTH) {
      int o = idx >> 6, j = idx & 63;
      double acc = 0.0;
#pragma unroll 8
      for (int i = 0; i < 64; ++i)
        acc = fma((double)Wks[o * 65 + i], (double)Xs[i * 65 + j], acc);
      Ys[o * 65 + j] = acc;
    }
    __syncthreads();
    // s_k = Y * W_k^T  [32 x 32]
    double* Sk = sm.sS[k];
    for (int idx = tid; idx < 1024; idx += NTH) {
      int o = idx >> 5, p = idx & 31;
      double acc = 0.0;
#pragma unroll 8
      for (int j = 0; j < 64; ++j)
        acc = fma(Ys[o * 65 + j], (double)Wks[p * 65 + j], acc);
      Sk[o * LDA + p] = acc;
    }
    __syncthreads();  // s_k done before W_k / Y overwritten
  }

  // ---- Phase 2: G0 = sum_k w_k s_k  (into sA; X/Y aliases dead) ----
  for (int idx = tid; idx < 1024; idx += NTH) {
    int i = idx >> 5, j = idx & 31;
    double g = 0.0;
#pragma unroll
    for (int k = 0; k < 4; ++k) g = fma(sm.wk[k], sm.sS[k][i * LDA + j], g);
    sm.sA[i * LDA + j] = g;
  }
  __syncthreads();

  // ---- Phase 3: eigh(G0) -> Sq, Si ----
  jacobi_eigh(sm.sA, sm.sV, sm, tid);
  for (int idx = tid; idx < 1024; idx += NTH) {
    int i = idx >> 5, m = idx & 31;
    sm.sT1[i * LDA + m] = sm.sV[i * LDA + m] * sqrt(fmax(sm.ew[m], 0.0));
  }
  __syncthreads();
  mm_nt(sm.sSq, sm.sT1, sm.sV, tid);
  __syncthreads();
  for (int idx = tid; idx < 1024; idx += NTH) {
    int i = idx >> 5, m = idx & 31;
    sm.sT1[i * LDA + m] = sm.sV[i * LDA + m] / sqrt(fmax(sm.ew[m], 1e-12));
  }
  __syncthreads();
  mm_nt(sm.sSi, sm.sT1, sm.sV, tid);
  __syncthreads();

  // ---- Phase 4/5: per k: T = Si s_k Si ; eigh ; U += w_k V log(L) V^T ----
  double* U = sm.sS[0];  // reuses s_0 slot once s_0 is consumed
  for (int k = 0; k < 4; ++k) {
    mm_nn(sm.sT1, sm.sSi, sm.sS[k], tid);
    __syncthreads();
    mm_nn(sm.sA, sm.sT1, sm.sSi, tid);
    __syncthreads();
    jacobi_eigh(sm.sA, sm.sV, sm, tid);
    for (int idx = tid; idx < 1024; idx += NTH) {
      int i = idx >> 5, m = idx & 31;
      sm.sT1[i * LDA + m] = sm.sV[i * LDA + m] * log(fmax(sm.ew[m], 1e-12));
    }
    __syncthreads();
    if (k == 0) mm_nt_ws<false>(U, sm.sT1, sm.sV, sm.wk[0], tid);
    else        mm_nt_ws<true >(U, sm.sT1, sm.sV, sm.wk[k], tid);
    __syncthreads();
  }

  // ---- Phase 6: eigh(U) -> E = expm(U) (into sSi) ----
  jacobi_eigh(U, sm.sV, sm, tid);
  for (int idx = tid; idx < 1024; idx += NTH) {
    int i = idx >> 5, m = idx & 31;
    sm.sT1[i * LDA + m] = sm.sV[i * LDA + m] * exp(sm.ew[m]);
  }
  __syncthreads();
  mm_nt(sm.sSi, sm.sT1, sm.sV, tid);  // E
  __syncthreads();

  // ---- Phase 7: out = Sq * E * Sq ----
  mm_nn(sm.sA, sm.sSq, sm.sSi, tid);  // T2 = Sq*E
  __syncthreads();
  float* outp = outg + (size_t)bc * 1024;
  for (int idx = tid; idx < 1024; idx += NTH) {
    int i = idx >> 5, j = idx & 31;
    double acc = 0.0;
#pragma unroll
    for (int m = 0; m < 32; ++m)
      acc = fma(sm.sA[i * LDA + m], sm.sSq[m * LDA + j], acc);
    outp[i * 32 + j] = (float)acc;
  }
}

extern "C" void kernel_launch(void* const* d_in, const int* in_sizes, int n_in,
                              void* d_out, int out_size, void* d_ws, size_t ws_size,
                              hipStream_t stream) {
  const float* x  = (const float*)d_in[0];   // [B,C,64,64] f32
  const float* w  = (const float*)d_in[1];   // [4] f32
  const float* Ws = (const float*)d_in[2];   // [4,32,64] f32
  float* out = (float*)d_out;                // [B,C,32,32] f32 (harness dtype)

  int nbc = in_sizes[0] / 4096;              // B*C = 2048
  mixedop_kernel<<<dim3(nbc), dim3(NTH), 0, stream>>>(x, w, Ws, out);
}